// Round 16
// baseline (37.996 us; speedup 1.0000x reference)
//
#include <hip/hip_runtime.h>
#include <hip/hip_bf16.h>
#include <math.h>

#define NPC   2048          // points per cloud
#define NC    8             // clouds
#define NTOT  (NPC * NC)    // 16384
#define KMAX  32
#define R2    0.04f         // f32(0.04) — boundary-exact vs numpy's f64 compare

typedef short bf16x8  __attribute__((ext_vector_type(8)));
typedef float f32x16  __attribute__((ext_vector_type(16)));

// f32 -> bf16 round-to-nearest-even (finite values only)
__device__ __forceinline__ unsigned int f2bf(float f) {
    unsigned int u = __float_as_uint(f);
    return (u + 0x7FFFu + ((u >> 16) & 1u)) >> 16;
}

// packed f32x2 -> bf16x2 (RNE), src0 in LOW half (validated round 5)
__device__ __forceinline__ unsigned int pkbf(float a, float b) {
    unsigned int r;
    asm("v_cvt_pk_bf16_f32 %0, %1, %2" : "=v"(r) : "v"(a), "v"(b));
    return r;
}

// count of set bits in m at positions < lane (wave64) — 2 VALU instrs
__device__ __forceinline__ int mbcnt64(unsigned long long m) {
    return (int)__builtin_amdgcn_mbcnt_hi((unsigned int)(m >> 32),
            __builtin_amdgcn_mbcnt_lo((unsigned int)m, 0u));
}

// ---- k-permuted epilogue (validated round 8): relu+pack 8 consecutive acc regs -> operand frag ----
// Weight k-rows pre-permuted by P(kk,hi,j) = (j&3)+4*hi+8*(2*(kk&1)+(j>>2))+32*(kk>>1).
__device__ __forceinline__ bf16x8 mk_frag(const f32x16& a, int off) {  // off: 0 or 8 (compile-time)
    int4 w;
    w.x = (int)pkbf(fmaxf(a[off+0],0.f), fmaxf(a[off+1],0.f));
    w.y = (int)pkbf(fmaxf(a[off+2],0.f), fmaxf(a[off+3],0.f));
    w.z = (int)pkbf(fmaxf(a[off+4],0.f), fmaxf(a[off+5],0.f));
    w.w = (int)pkbf(fmaxf(a[off+6],0.f), fmaxf(a[off+7],0.f));
    return __builtin_bit_cast(bf16x8, w);
}

// ============ kernel 1 (tiny): weight frags (k-permuted, validated r8/r9) + tail copies ============
__global__ __launch_bounds__(512) void prep_small(
    const float* __restrict__ pos, const int* __restrict__ batch,
    const float* __restrict__ W1, const float* __restrict__ b1,
    const float* __restrict__ W2, const float* __restrict__ b2,
    const float* __restrict__ W3,
    unsigned short* __restrict__ wf, float* __restrict__ out)
{
    int b = blockIdx.x, tid = threadIdx.x;
    if (b < 28) {
        int g = b * 512 + tid;                // 0..14335
        if (g < 1024) {
            int j = g & 7, lane = (g >> 3) & 63, t = g >> 9;
            int k = (lane >> 5)*8 + j, ch = t*32 + (lane & 31);
            float v = (k < 6) ? W1[k*64 + ch] : (k == 6 ? b1[ch] : 0.f);
            wf[g] = (unsigned short)f2bf(v);
        } else if (g < 6144) {
            int g2 = g - 1024;
            int j = g2 & 7, lane = (g2 >> 3) & 63, f = g2 >> 9;
            int t = f / 5, kk = f % 5;
            int hi = lane >> 5, row = t*32 + (lane & 31);
            float v;
            if (kk < 4) {
                int k = (j & 3) + 4*hi + 8*(2*(kk & 1) + (j >> 2)) + 32*(kk >> 1);
                v = W2[k*64 + row];
            } else {
                v = (hi == 0 && j == 0) ? b2[row] : 0.f;   // bias row, matches `onef` B-frag
            }
            wf[g] = (unsigned short)f2bf(v);
        } else {
            int g3 = g - 6144;
            int j = g3 & 7, lane = (g3 >> 3) & 63, f = g3 >> 9;
            int n = f >> 2, kk = f & 3;
            int hi = lane >> 5, col = n*32 + (lane & 31);
            int k = (j & 3) + 4*hi + 8*(2*(kk & 1) + (j >> 2)) + 32*(kk >> 1);
            wf[g] = (unsigned short)f2bf(W3[k*128 + col]);
        }
    } else {
        int i = (b - 28) * 512 + tid;
        if (i < NTOT*3) out[NTOT*128 + i] = pos[i];
        else            out[NTOT*131 + (i - NTOT*3)] = (float)batch[i - NTOT*3];
    }
}

// ============ kernel 2: FUSED search + MLP, 8 waves x Q=2 = 16 queries/block ============
// Every weight-frag ds_read feeds BOTH queries' MFMAs; every search point-read tests both
// queries. Fully inlined (no lambda, no dynamic indexing — r14's scratch trap avoided).
// LDS: sPxy4 16K + sPz2 8K + sW 26K + snbr 2K = 52 KB -> 2 blocks/CU = 16 waves/CU; VGPR<=128.
__global__ __launch_bounds__(512, 4) void fused_kernel(
    const float* __restrict__ x, const float* __restrict__ pos,
    const unsigned short* __restrict__ wf, const float* __restrict__ b3,
    float* __restrict__ out)
{
    __shared__ float4 sPxy4[NPC/2];   // 16384 B: {x(2k),y(2k),x(2k+1),y(2k+1)}
    __shared__ float2 sPz2[NPC/2];    //  8192 B: {z(2k), z(2k+1)}
    __shared__ int4   sW[1664];       // 26624 B: wg2a(640) | wg3b(1024)
    __shared__ int    snbr[8*64];     //  2048 B: per wave: [0..31] q0 slots, [32..63] q1 slots

    const int tid  = threadIdx.x;
    const int lane = tid & 63, wave = tid >> 6;
    const int e = lane & 31, hi = lane >> 5;
    const int q0    = __builtin_amdgcn_readfirstlane(blockIdx.x * 16 + wave * 2);
    const int base  = (q0 >> 11) << 11;           // cloud start row (q0,q1 same cloud)
    const int q0l   = q0 - base;                  // even local index
    const int wbase = wave << 6;

    // ---- Phase A: staging (512 threads; pos pairs then weight frags) ----
    {
        const float4* src = (const float4*)(pos + 3*base);   // 1536 float4 = 2048 points
        float4 f0 = src[3*tid], f1 = src[3*tid+1], f2 = src[3*tid+2];
        sPxy4[2*tid+0] = make_float4(f0.x, f0.y, f0.w, f1.x);
        sPz2 [2*tid+0] = make_float2(f0.z, f1.y);
        sPxy4[2*tid+1] = make_float4(f1.z, f1.w, f2.y, f2.z);
        sPz2 [2*tid+1] = make_float2(f2.x, f2.w);
    }
    {
        const int4* wsrc = (const int4*)(wf + 1024);
        #pragma unroll
        for (int it = 0; it < 4; ++it) {
            int idx = it*512 + tid;
            if (idx < 1664) sW[idx] = wsrc[idx];
        }
    }
    bf16x8 wA1_0 = *(const bf16x8*)(wf + (0*64 + lane)*8);
    bf16x8 wA1_1 = *(const bf16x8*)(wf + (1*64 + lane)*8);
    float b3v[4];
    #pragma unroll
    for (int n = 0; n < 4; ++n) b3v[n] = b3[n*32 + e];
    __syncthreads();   // the ONLY block-wide barrier

    // both query centers from ONE pair slot (q0l even)
    const float4 qv  = sPxy4[q0l >> 1];
    const float2 qzv = sPz2[q0l >> 1];
    const float q0x = qv.x, q0y = qv.y, q0z = qzv.x;
    const float q1x = qv.z, q1y = qv.w, q1z = qzv.y;

    // ---- Phase B: shared radius search, 2 points x 2 queries per lane-iter (r14-validated) ----
    int cnt0 = 0, cnt1 = 0;
    for (int j0 = 0; j0 < NPC && (cnt0 < KMAX || cnt1 < KMAX); j0 += 128) {
        float4 pp = sPxy4[(j0 >> 1) + lane];   // points A=j0+2*lane, B=A+1
        float2 zz = sPz2[(j0 >> 1) + lane];
        if (cnt0 < KMAX) {
            float dax = __fsub_rn(pp.x, q0x), day = __fsub_rn(pp.y, q0y), daz = __fsub_rn(zz.x, q0z);
            float dbx = __fsub_rn(pp.z, q0x), dby = __fsub_rn(pp.w, q0y), dbz = __fsub_rn(zz.y, q0z);
            float d2a = __fadd_rn(__fadd_rn(__fmul_rn(dax,dax), __fmul_rn(day,day)), __fmul_rn(daz,daz));
            float d2b = __fadd_rn(__fadd_rn(__fmul_rn(dbx,dbx), __fmul_rn(dby,dby)), __fmul_rn(dbz,dbz));
            bool va = d2a <= R2, vb = d2b <= R2;
            unsigned long long me = __ballot(va), mo = __ballot(vb);
            int se = cnt0 + mbcnt64(me) + mbcnt64(mo);
            int so = se + (va ? 1 : 0);
            if (va && se < KMAX) snbr[wbase + se] = j0 + 2*lane;
            if (vb && so < KMAX) snbr[wbase + so] = j0 + 2*lane + 1;
            cnt0 += (int)__popcll(me) + (int)__popcll(mo);
        }
        if (cnt1 < KMAX) {
            float dax = __fsub_rn(pp.x, q1x), day = __fsub_rn(pp.y, q1y), daz = __fsub_rn(zz.x, q1z);
            float dbx = __fsub_rn(pp.z, q1x), dby = __fsub_rn(pp.w, q1y), dbz = __fsub_rn(zz.y, q1z);
            float d2a = __fadd_rn(__fadd_rn(__fmul_rn(dax,dax), __fmul_rn(day,day)), __fmul_rn(daz,daz));
            float d2b = __fadd_rn(__fadd_rn(__fmul_rn(dbx,dbx), __fmul_rn(dby,dby)), __fmul_rn(dbz,dbz));
            bool va = d2a <= R2, vb = d2b <= R2;
            unsigned long long me = __ballot(va), mo = __ballot(vb);
            int se = cnt1 + mbcnt64(me) + mbcnt64(mo);
            int so = se + (va ? 1 : 0);
            if (va && se < KMAX) snbr[wbase + 32 + se] = j0 + 2*lane;
            if (vb && so < KMAX) snbr[wbase + 32 + so] = j0 + 2*lane + 1;
            cnt1 += (int)__popcll(me) + (int)__popcll(mo);
        }
    }
    if (cnt0 > KMAX) cnt0 = KMAX;
    if (cnt1 > KMAX) cnt1 = KMAX;

    // ---- Phase C: MLP, Q=2 interleaved, fully inlined ----
    int jl0 = (e < cnt0) ? snbr[wbase + e]      : q0l;
    int jl1 = (e < cnt1) ? snbr[wbase + 32 + e] : q0l + 1;
    float4 pv0 = sPxy4[jl0 >> 1];  float2 zv0 = sPz2[jl0 >> 1];
    float4 pv1 = sPxy4[jl1 >> 1];  float2 zv1 = sPz2[jl1 >> 1];
    bool o0 = (jl0 & 1) != 0, o1 = (jl1 & 1) != 0;
    float p0jx = o0 ? pv0.z : pv0.x, p0jy = o0 ? pv0.w : pv0.y, p0jz = o0 ? zv0.y : zv0.x;
    float p1jx = o1 ? pv1.z : pv1.x, p1jy = o1 ? pv1.w : pv1.y, p1jz = o1 ? zv1.y : zv1.x;
    int g0 = base + jl0, g1 = base + jl1;
    float x00 = x[3*g0], x01 = x[3*g0+1], x02 = x[3*g0+2];
    float x10 = x[3*g1], x11 = x[3*g1+1], x12 = x[3*g1+2];

    const unsigned int one_w = pkbf(1.0f, 0.0f);
    int4 ow = {0,0,0,0};
    if (!hi) ow.x = (int)one_w;
    const bf16x8 onef = __builtin_bit_cast(bf16x8, ow);   // GEMM2 bias-row B-frag

    int4 mw0, mw1;
    mw0.x = hi ? 0 : (int)pkbf(x00, x01);
    mw0.y = hi ? 0 : (int)pkbf(x02, p0jx - q0x);
    mw0.z = hi ? 0 : (int)pkbf(p0jy - q0y, p0jz - q0z);
    mw0.w = hi ? 0 : (int)one_w;
    mw1.x = hi ? 0 : (int)pkbf(x10, x11);
    mw1.y = hi ? 0 : (int)pkbf(x12, p1jx - q1x);
    mw1.z = hi ? 0 : (int)pkbf(p1jy - q1y, p1jz - q1z);
    mw1.w = hi ? 0 : (int)one_w;
    bf16x8 msg0 = __builtin_bit_cast(bf16x8, mw0);
    bf16x8 msg1 = __builtin_bit_cast(bf16x8, mw1);

    // layer1 (swapped), K=16 — 2 independent chains, shared A-frags
    __builtin_amdgcn_s_setprio(1);
    f32x16 lA0 = {}, lA1 = {}, lB0 = {}, lB1 = {};
    lA0 = __builtin_amdgcn_mfma_f32_32x32x16_bf16(wA1_0, msg0, lA0, 0, 0, 0);
    lB0 = __builtin_amdgcn_mfma_f32_32x32x16_bf16(wA1_0, msg1, lB0, 0, 0, 0);
    lA1 = __builtin_amdgcn_mfma_f32_32x32x16_bf16(wA1_1, msg0, lA1, 0, 0, 0);
    lB1 = __builtin_amdgcn_mfma_f32_32x32x16_bf16(wA1_1, msg1, lB1, 0, 0, 0);
    __builtin_amdgcn_s_setprio(0);
    bf16x8 h1f0[4], h1f1[4];
    h1f0[0] = mk_frag(lA0, 0); h1f0[1] = mk_frag(lA0, 8);
    h1f0[2] = mk_frag(lA1, 0); h1f0[3] = mk_frag(lA1, 8);
    h1f1[0] = mk_frag(lB0, 0); h1f1[1] = mk_frag(lB0, 8);
    h1f1[2] = mk_frag(lB1, 0); h1f1[3] = mk_frag(lB1, 8);

    // GEMM2 (swapped), K=80 — every frag read shared by both queries
    __builtin_amdgcn_s_setprio(1);
    f32x16 cA0 = {}, cA1 = {}, cB0 = {}, cB1 = {};
    #pragma unroll
    for (int kk = 0; kk < 4; ++kk) {
        bf16x8 wa = *(const bf16x8*)&sW[(0*5 + kk)*64 + lane];
        bf16x8 wb = *(const bf16x8*)&sW[(1*5 + kk)*64 + lane];
        cA0 = __builtin_amdgcn_mfma_f32_32x32x16_bf16(wa, h1f0[kk], cA0, 0, 0, 0);
        cB0 = __builtin_amdgcn_mfma_f32_32x32x16_bf16(wa, h1f1[kk], cB0, 0, 0, 0);
        cA1 = __builtin_amdgcn_mfma_f32_32x32x16_bf16(wb, h1f0[kk], cA1, 0, 0, 0);
        cB1 = __builtin_amdgcn_mfma_f32_32x32x16_bf16(wb, h1f1[kk], cB1, 0, 0, 0);
    }
    {
        bf16x8 wa = *(const bf16x8*)&sW[(0*5 + 4)*64 + lane];
        bf16x8 wb = *(const bf16x8*)&sW[(1*5 + 4)*64 + lane];
        cA0 = __builtin_amdgcn_mfma_f32_32x32x16_bf16(wa, onef, cA0, 0, 0, 0);
        cB0 = __builtin_amdgcn_mfma_f32_32x32x16_bf16(wa, onef, cB0, 0, 0, 0);
        cA1 = __builtin_amdgcn_mfma_f32_32x32x16_bf16(wb, onef, cA1, 0, 0, 0);
        cB1 = __builtin_amdgcn_mfma_f32_32x32x16_bf16(wb, onef, cB1, 0, 0, 0);
    }
    __builtin_amdgcn_s_setprio(0);
    bf16x8 h2f0[4], h2f1[4];
    h2f0[0] = mk_frag(cA0, 0); h2f0[1] = mk_frag(cA0, 8);
    h2f0[2] = mk_frag(cA1, 0); h2f0[3] = mk_frag(cA1, 8);
    h2f1[0] = mk_frag(cB0, 0); h2f1[1] = mk_frag(cB0, 8);
    h2f1[2] = mk_frag(cB1, 0); h2f1[3] = mk_frag(cB1, 8);

    // GEMM3 (non-swapped) + fused max — frag reads shared; bias in C-init
    const bool full0 = (cnt0 == 32), full1 = (cnt1 == 32);
    #pragma unroll
    for (int n = 0; n < 4; ++n) {
        f32x16 c, d;
        #pragma unroll
        for (int r = 0; r < 16; ++r) { c[r] = b3v[n]; d[r] = b3v[n]; }
        __builtin_amdgcn_s_setprio(1);
        #pragma unroll
        for (int kk = 0; kk < 4; ++kk) {
            bf16x8 bw = *(const bf16x8*)&sW[640 + (n*4 + kk)*64 + lane];
            c = __builtin_amdgcn_mfma_f32_32x32x16_bf16(h2f0[kk], bw, c, 0, 0, 0);
            d = __builtin_amdgcn_mfma_f32_32x32x16_bf16(h2f1[kk], bw, d, 0, 0, 0);
        }
        __builtin_amdgcn_s_setprio(0);
        float m0, m1;
        if (full0) {
            float t0 = fmaxf(fmaxf(c[0],  c[1]),  c[2]);
            float t1 = fmaxf(fmaxf(c[3],  c[4]),  c[5]);
            float t2 = fmaxf(fmaxf(c[6],  c[7]),  c[8]);
            float t3 = fmaxf(fmaxf(c[9],  c[10]), c[11]);
            float t4 = fmaxf(fmaxf(c[12], c[13]), c[14]);
            m0 = fmaxf(fmaxf(t0, t1), c[15]);
            m0 = fmaxf(fmaxf(m0, t2), t3);
            m0 = fmaxf(m0, t4);
        } else {
            m0 = -INFINITY;
            #pragma unroll
            for (int reg = 0; reg < 16; ++reg) {
                int r = (reg & 3) + 8*(reg >> 2) + 4*hi;
                m0 = fmaxf(m0, (r < cnt0) ? c[reg] : -INFINITY);
            }
        }
        if (full1) {
            float t0 = fmaxf(fmaxf(d[0],  d[1]),  d[2]);
            float t1 = fmaxf(fmaxf(d[3],  d[4]),  d[5]);
            float t2 = fmaxf(fmaxf(d[6],  d[7]),  d[8]);
            float t3 = fmaxf(fmaxf(d[9],  d[10]), d[11]);
            float t4 = fmaxf(fmaxf(d[12], d[13]), d[14]);
            m1 = fmaxf(fmaxf(t0, t1), d[15]);
            m1 = fmaxf(fmaxf(m1, t2), t3);
            m1 = fmaxf(m1, t4);
        } else {
            m1 = -INFINITY;
            #pragma unroll
            for (int reg = 0; reg < 16; ++reg) {
                int r = (reg & 3) + 8*(reg >> 2) + 4*hi;
                m1 = fmaxf(m1, (r < cnt1) ? d[reg] : -INFINITY);
            }
        }
        m0 = fmaxf(m0, __shfl_xor(m0, 32));
        m1 = fmaxf(m1, __shfl_xor(m1, 32));
        if (hi == 0) {
            out[q0*128 + n*32 + e]       = m0;
            out[(q0+1)*128 + n*32 + e]   = m1;
        }
    }
}

extern "C" void kernel_launch(void* const* d_in, const int* in_sizes, int n_in,
                              void* d_out, int out_size, void* d_ws, size_t ws_size,
                              hipStream_t stream) {
    const float* x     = (const float*)d_in[0];
    const float* pos   = (const float*)d_in[1];
    const int*   batch = (const int*)d_in[2];
    const float* W1    = (const float*)d_in[3];
    const float* b1    = (const float*)d_in[4];
    const float* W2    = (const float*)d_in[5];
    const float* b2    = (const float*)d_in[6];
    const float* W3    = (const float*)d_in[7];
    const float* b3    = (const float*)d_in[8];
    float* out = (float*)d_out;

    unsigned short* wfrag = (unsigned short*)d_ws;   // 14336 bf16 (28 KB)

    prep_small<<<156, 512, 0, stream>>>(pos, batch, W1, b1, W2, b2, W3, wfrag, out);
    fused_kernel<<<NTOT / 16, 512, 0, stream>>>(x, pos, wfrag, b3, out);
}